// Round 1
// baseline (436.797 us; speedup 1.0000x reference)
//
#include <hip/hip_runtime.h>

#define WINDOW 128
#define H 32
#define O2 256
#define LFRAMES 65536
#define F_PER_BLK 64
#define WU 32
#define SSTG 96   // staged frames per block (WU + F_PER_BLK)

__device__ __forceinline__ float selu_f(float x) {
    const float scale = 1.0507009873554805f;
    const float alpha = 1.6732632423543772f;
    return scale * (x > 0.0f ? x : alpha * (expf(x) - 1.0f));
}

// ---------------------------------------------------------------------------
// Kernel A: x -> y2 (post-MLP activations) and u2 (B2 @ y2), written to ws.
// Per block: 64 output frames, 32 warmup frames (|lam|^32 ~ 1e-14 => exact
// to fp32; chunk 0 exact via zero-fill).
// ---------------------------------------------------------------------------
__global__ __launch_bounds__(256, 2)
void lru_stage1(const float* __restrict__ x,
                const float* __restrict__ b1r, const float* __restrict__ b1i,
                const float* __restrict__ nu1, const float* __restrict__ th1,
                const float* __restrict__ c1r, const float* __restrict__ c1i,
                const float* __restrict__ d1,
                const float* __restrict__ mlp_w, const float* __restrict__ mlp_b,
                const float* __restrict__ b2r, const float* __restrict__ b2i,
                float* __restrict__ y2ws, float* __restrict__ u2ws)
{
    // LDS pool (58368 B), phase-overlapped regions:
    //  [0,12288)   xsT   float4[32][96]   (phases 1-2)
    //  [0,6336)    P     [96][66]  u1 re/im interleaved (phase 2w-3)
    //  [6336,8448) d1x   [64][33]         (phase 2w-4)
    //  [8448,12544) h1   [64][64]         (phase 3-4)
    //  [12544,14592) lam1p [32][64]       (phase 0-3)
    //  [0,2048)    zbuf  [64][32]         (phase 4-5, dead-P space)
    //  [2048,4096) y2l   [64][32]         (phase 5-6, dead-P space)
    __shared__ float smem[14592];
    float4* xsT   = (float4*)smem;
    float*  P     = smem;
    float*  d1x   = smem + 6336;
    float*  h1    = smem + 8448;
    float*  lam1p = smem + 12544;
    float*  zbuf  = smem;
    float*  y2l   = smem + 2048;

    const int tid = threadIdx.x;
    const int bid = blockIdx.x;
    const int t0 = bid * F_PER_BLK;
    const int frame0 = t0 - WU;

    // phase 0: lambda1 powers (gamma folded in): lam1p[j] = gamma * lam^j
    if (tid < H) {
        float enu = expf(nu1[tid]);
        float mag = expf(-enu);
        float ang = expf(th1[tid]);
        float lr = mag * cosf(ang), li = mag * sinf(ang);
        float g = sqrtf(fmaxf(1.0f - mag * mag, 0.0f));
        float pr = g, pi = 0.0f;
        for (int j = 0; j < WU; ++j) {
            lam1p[j * 64 + 2 * tid]     = pr;
            lam1p[j * 64 + 2 * tid + 1] = pi;
            float npr = pr * lr - pi * li;
            float npi = pr * li + pi * lr;
            pr = npr; pi = npi;
        }
    }

    // phase 1: stage x into LDS, transposed: xsT[k4][f] = frame f, floats 4k4..4k4+3
    for (int p = 0; p < 12; ++p) {
        int idx = tid + 256 * p;
        int f = idx >> 5;
        int k4 = idx & 31;
        int gf = frame0 + f;
        float4 v = make_float4(0.f, 0.f, 0.f, 0.f);
        if (gf >= 0) v = *(const float4*)(x + (size_t)gf * WINDOW + 4 * k4);
        xsT[k4 * 96 + f] = v;
    }
    __syncthreads();

    // phase 2: P rows = [u1re/u1im interleaved (64)] then d1x (32).
    // 768 items = 96 frames x 8 row-groups of 12; 3 items/thread.
    float acc[3][12];
    #pragma unroll
    for (int i = 0; i < 3; ++i) {
        int it = tid + 256 * i;
        int f = it % 96;
        int ro = it / 96;
        const float* wp[12];
        #pragma unroll
        for (int m = 0; m < 12; ++m) {
            int r = ro * 12 + m;   // r&1 == m&1 (12 even) -> folds at compile time
            wp[m] = (r < 64) ? (((m & 1) ? b1i : b1r) + (r >> 1) * WINDOW)
                             : (d1 + (r - 64) * WINDOW);
            acc[i][m] = 0.f;
        }
        for (int k4 = 0; k4 < 32; ++k4) {
            float4 xv = xsT[k4 * 96 + f];
            #pragma unroll
            for (int m = 0; m < 12; ++m) {
                float4 wv = *(const float4*)(wp[m] + 4 * k4);
                acc[i][m] = fmaf(wv.x, xv.x, acc[i][m]);
                acc[i][m] = fmaf(wv.y, xv.y, acc[i][m]);
                acc[i][m] = fmaf(wv.z, xv.z, acc[i][m]);
                acc[i][m] = fmaf(wv.w, xv.w, acc[i][m]);
            }
        }
    }
    __syncthreads();   // all xsT reads done; safe to overwrite with P/d1x
    #pragma unroll
    for (int i = 0; i < 3; ++i) {
        int it = tid + 256 * i;
        int f = it % 96;
        int ro = it / 96;
        #pragma unroll
        for (int m = 0; m < 12; ++m) {
            int r = ro * 12 + m;
            if (r < 64) P[f * 66 + r] = acc[i][m];
            else if (f >= WU) d1x[(f - WU) * 33 + (r - 64)] = acc[i][m];
        }
    }
    __syncthreads();

    // phase 3: h1 = windowed conv + per-thread sequential scan (8 consecutive frames)
    {
        int c = tid & 31;
        int fg = tid >> 5;
        float enu = expf(nu1[c]);
        float mag = expf(-enu);
        float ang = expf(th1[c]);
        float lr = mag * cosf(ang), li = mag * sinf(ang);
        float g = sqrtf(fmaxf(1.0f - mag * mag, 0.0f));
        int f0 = WU + fg * 8;   // staged index of first frame in this group
        float hre = 0.f, him = 0.f;
        for (int j = 0; j < WU; ++j) {
            float2 lp = *(const float2*)(lam1p + j * 64 + 2 * c);
            float2 u  = *(const float2*)(P + (f0 - j) * 66 + 2 * c);
            hre = fmaf(lp.x, u.x, hre); hre = fmaf(-lp.y, u.y, hre);
            him = fmaf(lp.x, u.y, him); him = fmaf(lp.y, u.x, him);
        }
        h1[(fg * 8) * 64 + 2 * c]     = hre;
        h1[(fg * 8) * 64 + 2 * c + 1] = him;
        for (int s = 1; s < 8; ++s) {
            float2 u = *(const float2*)(P + (f0 + s) * 66 + 2 * c);
            float nre = lr * hre - li * him + g * u.x;
            float nim = lr * him + li * hre + g * u.y;
            hre = nre; him = nim;
            h1[(fg * 8 + s) * 64 + 2 * c]     = hre;
            h1[(fg * 8 + s) * 64 + 2 * c + 1] = him;
        }
    }
    __syncthreads();

    // phase 4: y1 = Re(C1 h1) + D1 x, selu -> zbuf
    for (int p = 0; p < 8; ++p) {
        int c = tid & 31;
        int fi = (tid >> 5) + 8 * p;
        float y = d1x[fi * 33 + c];
        const float4* crp = (const float4*)(c1r + c * H);
        const float4* cip = (const float4*)(c1i + c * H);
        const float4* hp  = (const float4*)(h1 + fi * 64);
        #pragma unroll
        for (int h2 = 0; h2 < 8; ++h2) {
            float4 cr = crp[h2], ci = cip[h2];
            float4 ha = hp[2 * h2], hb = hp[2 * h2 + 1];
            y = fmaf(cr.x, ha.x, y); y = fmaf(-ci.x, ha.y, y);
            y = fmaf(cr.y, ha.z, y); y = fmaf(-ci.y, ha.w, y);
            y = fmaf(cr.z, hb.x, y); y = fmaf(-ci.z, hb.y, y);
            y = fmaf(cr.w, hb.z, y); y = fmaf(-ci.w, hb.w, y);
        }
        zbuf[fi * 32 + c] = selu_f(y);
    }
    __syncthreads();

    // phase 5: MLP + selu -> y2l (LDS) and y2ws (global)
    for (int p = 0; p < 8; ++p) {
        int c = tid & 31;
        int fi = (tid >> 5) + 8 * p;
        float m = mlp_b[c];
        #pragma unroll 4
        for (int h = 0; h < H; ++h)
            m = fmaf(zbuf[fi * 32 + h], mlp_w[h * 32 + c], m);
        float v = selu_f(m);
        y2l[fi * 32 + c] = v;
        y2ws[(size_t)(t0 + fi) * H + c] = v;
    }
    __syncthreads();

    // phase 6: u2 = B2 @ y2 (raw, gamma folded into lam2p in kernel B)
    for (int p = 0; p < 8; ++p) {
        int c = tid & 31;
        int fi = (tid >> 5) + 8 * p;
        float re = 0.f, im = 0.f;
        const float4* brp = (const float4*)(b2r + c * H);
        const float4* bip = (const float4*)(b2i + c * H);
        const float4* yp  = (const float4*)(y2l + fi * 32);
        #pragma unroll
        for (int h2 = 0; h2 < 8; ++h2) {
            float4 br = brp[h2], bi = bip[h2], yv = yp[h2];
            re = fmaf(br.x, yv.x, re); re = fmaf(br.y, yv.y, re);
            re = fmaf(br.z, yv.z, re); re = fmaf(br.w, yv.w, re);
            im = fmaf(bi.x, yv.x, im); im = fmaf(bi.y, yv.y, im);
            im = fmaf(bi.z, yv.z, im); im = fmaf(bi.w, yv.w, im);
        }
        float2 o; o.x = re; o.y = im;
        *(float2*)(u2ws + (size_t)(t0 + fi) * 2 * H + 2 * c) = o;
    }
}

// ---------------------------------------------------------------------------
// Kernel B: y2/u2 -> out = Re(C2 h2) + D2 y2
// ---------------------------------------------------------------------------
__global__ __launch_bounds__(256, 2)
void lru_stage2(const float* __restrict__ y2ws, const float* __restrict__ u2ws,
                const float* __restrict__ nu2, const float* __restrict__ th2,
                const float* __restrict__ c2r, const float* __restrict__ c2i,
                const float* __restrict__ d2,
                float* __restrict__ out)
{
    // LDS (62080 B): y2s [96][33] | u2s [96][64] | h2 [64][65] | lam2p [32][64]
    __shared__ float smem[15520];
    float* y2s   = smem;
    float* u2s   = smem + 3168;
    float* h2    = smem + 9312;
    float* lam2p = smem + 13472;

    const int tid = threadIdx.x;
    const int bid = blockIdx.x;
    const int t0 = bid * F_PER_BLK;
    const int frame0 = t0 - WU;

    if (tid < H) {
        float enu = expf(nu2[tid]);
        float mag = expf(-enu);
        float ang = expf(th2[tid]);
        float lr = mag * cosf(ang), li = mag * sinf(ang);
        float g = sqrtf(fmaxf(1.0f - mag * mag, 0.0f));
        float pr = g, pi = 0.0f;
        for (int j = 0; j < WU; ++j) {
            lam2p[j * 64 + 2 * tid]     = pr;
            lam2p[j * 64 + 2 * tid + 1] = pi;
            float npr = pr * lr - pi * li;
            float npi = pr * li + pi * lr;
            pr = npr; pi = npi;
        }
    }

    for (int p = 0; p < 12; ++p) {
        int idx = tid + 256 * p;
        int f = idx >> 5, c = idx & 31;
        int gf = frame0 + f;
        y2s[f * 33 + c] = (gf >= 0) ? y2ws[(size_t)gf * H + c] : 0.f;
    }
    for (int p = 0; p < 12; ++p) {
        int idx = tid + 256 * p;
        int f = idx >> 5, j = idx & 31;
        int gf = frame0 + f;
        float2 v = make_float2(0.f, 0.f);
        if (gf >= 0) v = *(const float2*)(u2ws + (size_t)gf * 2 * H + 2 * j);
        *(float2*)(u2s + f * 64 + 2 * j) = v;
    }
    __syncthreads();

    // conv2 + scan
    {
        int c = tid & 31;
        int fg = tid >> 5;
        float enu = expf(nu2[c]);
        float mag = expf(-enu);
        float ang = expf(th2[c]);
        float lr = mag * cosf(ang), li = mag * sinf(ang);
        float g = sqrtf(fmaxf(1.0f - mag * mag, 0.0f));
        int f0 = WU + fg * 8;
        float hre = 0.f, him = 0.f;
        for (int j = 0; j < WU; ++j) {
            float2 lp = *(const float2*)(lam2p + j * 64 + 2 * c);
            float2 u  = *(const float2*)(u2s + (f0 - j) * 64 + 2 * c);
            hre = fmaf(lp.x, u.x, hre); hre = fmaf(-lp.y, u.y, hre);
            him = fmaf(lp.x, u.y, him); him = fmaf(lp.y, u.x, him);
        }
        h2[(fg * 8) * 65 + 2 * c]     = hre;
        h2[(fg * 8) * 65 + 2 * c + 1] = him;
        for (int s = 1; s < 8; ++s) {
            float2 u = *(const float2*)(u2s + (f0 + s) * 64 + 2 * c);
            float nre = lr * hre - li * him + g * u.x;
            float nim = lr * him + li * hre + g * u.y;
            hre = nre; him = nim;
            h2[(fg * 8 + s) * 65 + 2 * c]     = hre;
            h2[(fg * 8 + s) * 65 + 2 * c + 1] = him;
        }
    }
    __syncthreads();

    // output GEMM: out[o][t] = sum_h c2r*h2re - c2i*h2im + d2*y2
    {
        int f = tid & 63;
        int og = __builtin_amdgcn_readfirstlane(tid >> 6);  // wave-uniform
        for (int oc = 0; oc < 4; ++oc) {
            int obase = og * 64 + oc * 16;
            const float* c2r_b = c2r + (size_t)obase * H;
            const float* c2i_b = c2i + (size_t)obase * H;
            const float* d2_b  = d2  + (size_t)obase * H;
            float acc[16];
            #pragma unroll
            for (int i = 0; i < 16; ++i) acc[i] = 0.f;
            for (int h = 0; h < H; ++h) {
                float zr  = h2[f * 65 + 2 * h];
                float nzi = -h2[f * 65 + 2 * h + 1];
                float zy  = y2s[(f + WU) * 33 + h];
                #pragma unroll
                for (int i = 0; i < 16; ++i) {
                    float a = fmaf(c2r_b[i * H + h], zr, acc[i]);
                    a = fmaf(c2i_b[i * H + h], nzi, a);
                    acc[i] = fmaf(d2_b[i * H + h], zy, a);
                }
            }
            #pragma unroll
            for (int i = 0; i < 16; ++i)
                out[(size_t)(obase + i) * LFRAMES + t0 + f] = acc[i];
        }
    }
}

extern "C" void kernel_launch(void* const* d_in, const int* in_sizes, int n_in,
                              void* d_out, int out_size, void* d_ws, size_t ws_size,
                              hipStream_t stream)
{
    const float* x     = (const float*)d_in[0];
    const float* b1r   = (const float*)d_in[1];
    const float* b1i   = (const float*)d_in[2];
    const float* nu1   = (const float*)d_in[3];
    const float* th1   = (const float*)d_in[4];
    const float* c1r   = (const float*)d_in[5];
    const float* c1i   = (const float*)d_in[6];
    const float* d1    = (const float*)d_in[7];
    const float* mlp_w = (const float*)d_in[8];
    const float* mlp_b = (const float*)d_in[9];
    const float* b2r   = (const float*)d_in[10];
    const float* b2i   = (const float*)d_in[11];
    const float* nu2   = (const float*)d_in[12];
    const float* th2   = (const float*)d_in[13];
    const float* c2r   = (const float*)d_in[14];
    const float* c2i   = (const float*)d_in[15];
    const float* d2    = (const float*)d_in[16];
    float* out = (float*)d_out;

    float* y2ws = (float*)d_ws;                          //  8 MB
    float* u2ws = y2ws + (size_t)LFRAMES * H;            // 16 MB

    dim3 blk(256);
    dim3 grid(LFRAMES / F_PER_BLK);   // 1024 blocks

    lru_stage1<<<grid, blk, 0, stream>>>(x, b1r, b1i, nu1, th1, c1r, c1i, d1,
                                         mlp_w, mlp_b, b2r, b2i, y2ws, u2ws);
    lru_stage2<<<grid, blk, 0, stream>>>(y2ws, u2ws, nu2, th2, c2r, c2i, d2, out);
}